// Round 9
// baseline (176.776 us; speedup 1.0000x reference)
//
#include <hip/hip_runtime.h>
#include <hip/hip_bf16.h>
#include <math.h>

// Problem constants
#define BATCH 8192
#define HD    256
#define NPTS  51              // nb_steps=50 -> 51 quadrature points
#define NK2   1639            // ceil(8192/5) blocks, 5 batches (255 rows) each

typedef __bf16 bf16x8 __attribute__((ext_vector_type(8)));
typedef float  f32x4  __attribute__((ext_vector_type(4)));

// ---- workspace layout (bytes) ----
#define OFF_IW2P  0            // 65536 ushort: iw2 bf16, CHUNK-MAJOR per col-half:
                               //   iw2p[h*32768 + c*1024 + n*8 + j] = bf16(iw2[(h*128+n)*256 + c*8 + j])
#define OFF_W1X   131072       // 256 f32 (iw1[:,0])
#define OFF_CC    132096       // 64 f32
#define OFF_STEPS 132352       // 64 f32
#define OFF_OFFS  132608       // 8192 f32
#define OFF_SCAL  165376       // 8192 f32
#define OFF_G1    198144       // 8192*256 f32 (+ slack beyond for OOB-staging of last block)

__device__ __forceinline__ unsigned short f2bf(float f) {
    union { float f; unsigned u; } v; v.f = f;
    unsigned r = v.u + 0x7FFFu + ((v.u >> 16) & 1u);   // RTNE
    return (unsigned short)(r >> 16);
}

__device__ __forceinline__ unsigned pk2bf(float lo, float hi) {
    __hip_bfloat162 t = __float22bfloat162_rn(float2{lo, hi});
    union { __hip_bfloat162 b; unsigned u; } v; v.b = t;
    return v.u;
}

// ---------------- K1: nnet (64-batch MFMA blocks) + repack + consts + g1 ----------------
// R18: nnet redundancy cut 4x (64-batch tiles: nw2 float traffic 128MB->32MB)
// and placed FIRST in k1's grid where the 769 tiny repack/g1 blocks leave idle
// CUs (R8 showed nnet costs ~19us when embedded in k2's GEMM grid).
__global__ void k1_prep(const float* __restrict__ iw2, const float* __restrict__ iw1,
                        const float* __restrict__ ib1, const float* __restrict__ h,
                        const float* __restrict__ nw1, const float* __restrict__ nb1,
                        const float* __restrict__ nw2, const float* __restrict__ nb2,
                        const float* __restrict__ nw3, const float* __restrict__ nb3,
                        unsigned short* iw2p, float* w1xs, float* cc, float* steps,
                        float* __restrict__ g1, float* __restrict__ offs,
                        float* __restrict__ scal) {
    __shared__ __align__(16) unsigned char sm1[39680];
    int blk = blockIdx.x, tid = threadIdx.x;
    int lane = tid & 63, w = tid >> 6, l16 = lane & 15, quad = lane >> 4;

    if (blk < 128) {
        // ---- nnet: offs/scal for 64 batches [blk*64, +64) ----
        float* hs = (float*)sm1;                               // [960]
        unsigned short* a1s = (unsigned short*)(sm1 + 3840);   // [64][264]
        float* Pn = (float*)(sm1 + 3840 + 33792);              // [4][2][64]
        int b0 = blk * 64;
        for (int i = tid; i < 960; i += 256) hs[i] = h[b0 * 15 + i];
        __syncthreads();
        {
            int n = tid;
            float nr[15];
            #pragma unroll
            for (int j = 0; j < 15; ++j) nr[j] = nw1[n * 15 + j];
            float bn = nb1[n];
            #pragma unroll 4
            for (int bb = 0; bb < 64; ++bb) {
                float a = bn;
                #pragma unroll
                for (int j = 0; j < 15; ++j) a += hs[bb * 15 + j] * nr[j];
                a1s[bb * 264 + n] = f2bf(fmaxf(a, 0.f));
            }
        }
        __syncthreads();
        f32x4 acc[4][4];
        #pragma unroll
        for (int mt = 0; mt < 4; ++mt)
            #pragma unroll
            for (int nt = 0; nt < 4; ++nt) acc[mt][nt] = (f32x4){0.f, 0.f, 0.f, 0.f};
        #pragma unroll 2
        for (int ks = 0; ks < 8; ++ks) {
            bf16x8 af[4];
            #pragma unroll
            for (int mt = 0; mt < 4; ++mt)
                af[mt] = *(const bf16x8*)&a1s[(mt * 16 + l16) * 264 + ks * 32 + quad * 8];
            #pragma unroll
            for (int nt = 0; nt < 4; ++nt) {
                const float* np = nw2 + (w * 64 + nt * 16 + l16) * 256 + ks * 32 + quad * 8;
                float4 f0 = ((const float4*)np)[0];
                float4 f1 = ((const float4*)np)[1];
                union { uint4 u; bf16x8 v; } bf;
                bf.u.x = pk2bf(f0.x, f0.y); bf.u.y = pk2bf(f0.z, f0.w);
                bf.u.z = pk2bf(f1.x, f1.y); bf.u.w = pk2bf(f1.z, f1.w);
                #pragma unroll
                for (int mt = 0; mt < 4; ++mt)
                    acc[mt][nt] = __builtin_amdgcn_mfma_f32_16x16x32_bf16(af[mt], bf.v, acc[mt][nt], 0, 0, 0);
            }
        }
        float p0[4][4], p1[4][4];
        #pragma unroll
        for (int mt = 0; mt < 4; ++mt)
            #pragma unroll
            for (int i = 0; i < 4; ++i) { p0[mt][i] = 0.f; p1[mt][i] = 0.f; }
        #pragma unroll
        for (int nt = 0; nt < 4; ++nt) {
            int nn = w * 64 + nt * 16 + l16;
            float bias = nb2[nn], wa = nw3[nn], wb = nw3[256 + nn];
            #pragma unroll
            for (int mt = 0; mt < 4; ++mt)
                #pragma unroll
                for (int i = 0; i < 4; ++i) {
                    float v = acc[mt][nt][i] + bias;
                    v = v > 0.f ? v : 0.f;
                    p0[mt][i] += v * wa;
                    p1[mt][i] += v * wb;
                }
        }
        #pragma unroll
        for (int mask = 1; mask < 16; mask <<= 1)
            #pragma unroll
            for (int mt = 0; mt < 4; ++mt)
                #pragma unroll
                for (int i = 0; i < 4; ++i) {
                    p0[mt][i] += __shfl_xor(p0[mt][i], mask, 64);
                    p1[mt][i] += __shfl_xor(p1[mt][i], mask, 64);
                }
        if (l16 == 0) {
            #pragma unroll
            for (int mt = 0; mt < 4; ++mt)
                #pragma unroll
                for (int i = 0; i < 4; ++i) {
                    int r = mt * 16 + quad * 4 + i;      // batch-local 0..63
                    Pn[w * 128 + r]      = p0[mt][i];
                    Pn[w * 128 + 64 + r] = p1[mt][i];
                }
        }
        __syncthreads();
        if (tid < 64) {
            float s0 = Pn[tid]       + Pn[128 + tid]      + Pn[256 + tid]      + Pn[384 + tid]      + nb3[0];
            float s1 = Pn[64 + tid]  + Pn[128 + 64 + tid] + Pn[256 + 64 + tid] + Pn[384 + 64 + tid] + nb3[1];
            offs[b0 + tid] = s0;
            scal[b0 + tid] = __expf(s1);
        }
    } else if (blk < 384) {
        int t = (blk - 128) * 256 + tid;   // t = n*256 + k
        int n = t >> 8, k = t & 255;
        int half = n >> 7, nl = n & 127, c = k >> 3, j = k & 7;
        iw2p[half * 32768 + c * 1024 + nl * 8 + j] = f2bf(iw2[t]);
    } else if (blk == 384) {
        w1xs[tid] = iw1[tid * 16];   // column 0 of iw1
        const float PI_F = 3.14159265358979323846f;
        if (tid <= 50) {
            int j = tid;
            float s = 0.f;
            for (int i = 0; i <= 50; i += 2) {          // odd i have W=0
                float w2 = (i == 0) ? 1.f : 2.f / (1.f - (float)(i * i));
                float l;
                if (j == 0 || j == 50) l = 0.5f;
                else { int r = (i * j) % 100; l = __cosf((float)r * (PI_F / 50.f)); }
                s += l * w2;
            }
            cc[j]    = s * (2.f / 50.f);
            steps[j] = __cosf((float)j * (PI_F / 50.f));
        }
    } else {
        float* hsg = (float*)sm1;          // [16][15]
        int b0 = (blk - 385) * 16, n = tid;
        if (tid < 240) { int bb = tid / 15, j = tid % 15; hsg[bb * 15 + j] = h[(b0 + bb) * 15 + j]; }
        __syncthreads();
        float ir[16];
        const float4* ip = (const float4*)(iw1 + n * 16);
        ((float4*)ir)[0] = ip[0]; ((float4*)ir)[1] = ip[1];
        ((float4*)ir)[2] = ip[2]; ((float4*)ir)[3] = ip[3];
        float bi = ib1[n];
        #pragma unroll
        for (int bb = 0; bb < 16; ++bb) {
            float g = bi;
            #pragma unroll
            for (int j = 0; j < 15; ++j) g += hsg[bb * 15 + j] * ir[j + 1];
            g1[(b0 + bb) * 256 + n] = g;
        }
    }
}

// ---------------- k2: 5-batch (255-row) GEMM block, full in-block finish ----------------
// R18: R1's proven per-wave body (acc[2][16], ~108 VGPR, no spill) at 512 thr
// / 8 waves / 256 rows. 256 rows = exactly 5 batches x 51 points (+1 dead
// row), so the quadrature reduction completes IN-BLOCK with plain stores to
// out[] — fv array, k4 kernel, and their ~10us of wall are deleted. B
// streamed in 4x32KB dbuf chunks as before.
__launch_bounds__(512, 2)
__global__ void k2_main(const float* __restrict__ x, const float* __restrict__ g1,
                        const float* __restrict__ w1xs, const unsigned short* __restrict__ iw2p,
                        const float* __restrict__ ib2, const float* __restrict__ iw3,
                        const float* __restrict__ steps, const float* __restrict__ cc,
                        const float* __restrict__ ib3, const float* __restrict__ offs,
                        const float* __restrict__ scal,
                        float* __restrict__ out) {
    __shared__ __align__(16) unsigned char smem[72704];   // [0,64K) B dbuf | [64K,+6K) g1 | [+1K) w1x
    float* Pp = (float*)smem;                             // epilogue alias: [256][20] f32
    float* Cc = (float*)(smem + 20480);                   // epilogue alias: [256] f32

    int tid = threadIdx.x;
    int bb  = blockIdx.x;
    int lane = tid & 63, w = tid >> 6;
    int l16 = lane & 15, quad = lane >> 4;
    int blo = bb * 5;                                     // first batch of this block

    const unsigned char* bbase = (const unsigned char*)iw2p;

    // DMA B chunk 0 (both halves, 32KB) into buf 0, g1 rows blo..blo+5 (6KB), w1x (1KB)
    #pragma unroll
    for (int hf = 0; hf < 2; ++hf)
        #pragma unroll
        for (int it = 0; it < 2; ++it)
            __builtin_amdgcn_global_load_lds(
                (const __attribute__((address_space(1))) unsigned int*)(bbase + hf * 65536 + tid * 16 + it * 8192),
                (__attribute__((address_space(3))) unsigned int*)(smem + hf * 16384 + tid * 16 + it * 8192),
                16, 0, 0);
    if (tid < 384)
        __builtin_amdgcn_global_load_lds(
            (const __attribute__((address_space(1))) unsigned int*)((const unsigned char*)(g1 + blo * 256) + tid * 16),
            (__attribute__((address_space(3))) unsigned int*)(smem + 65536 + tid * 16),
            16, 0, 0);
    if (tid < 64)
        __builtin_amdgcn_global_load_lds(
            (const __attribute__((address_space(1))) unsigned int*)((const unsigned char*)w1xs + tid * 16),
            (__attribute__((address_space(3))) unsigned int*)(smem + 71680 + tid * 16),
            16, 0, 0);

    // per-row constants: local batch, point, x-scale (overlaps DMA)
    float xs_[2]; int rel_[2];
    #pragma unroll
    for (int mt = 0; mt < 2; ++mt) {
        int r = w * 32 + mt * 16 + l16;                   // 0..255
        unsigned bl = (unsigned)(((unsigned long long)(unsigned)r * 657931ull) >> 25);  // r/51
        int p = r - (int)bl * 51;
        int bg = blo + (int)bl; if (bg > BATCH - 1) bg = BATCH - 1;
        xs_[mt] = x[bg] * (steps[p] + 1.f) * 0.5f;
        rel_[mt] = (int)bl * 256;
    }

    f32x4 acc[2][16];
    #pragma unroll
    for (int mt = 0; mt < 2; ++mt)
        #pragma unroll
        for (int nt = 0; nt < 16; ++nt)
            acc[mt][nt] = (f32x4){0.f, 0.f, 0.f, 0.f};

    const float* Ag = (const float*)(smem + 65536);   // [6][256] g1 rows
    const float* Wl = (const float*)(smem + 71680);   // [256] w1x

    #pragma unroll
    for (int kc = 0; kc < 4; ++kc) {
        __syncthreads();                       // DMA(kc) drained + all waves aligned
        if (kc < 3) {                          // prefetch next chunk (both halves) into other buf
            #pragma unroll
            for (int hf = 0; hf < 2; ++hf)
                #pragma unroll
                for (int it = 0; it < 2; ++it)
                    __builtin_amdgcn_global_load_lds(
                        (const __attribute__((address_space(1))) unsigned int*)(bbase + hf * 65536 + (kc + 1) * 16384 + tid * 16 + it * 8192),
                        (__attribute__((address_space(3))) unsigned int*)(smem + ((kc + 1) & 1) * 32768 + hf * 16384 + tid * 16 + it * 8192),
                        16, 0, 0);
        }
        #pragma unroll
        for (int s = 0; s < 2; ++s) {
            int ks = kc * 2 + s;               // global 32-wide k-step 0..7
            int ko = ks * 32 + quad * 8;
            int cl = s * 4 + quad;             // chunk-local c 0..7

            // ---- A fragments ONCE per k-step (af[2] = 8 VGPRs) ----
            union { uint4 u; bf16x8 v; } af[2];
            {
                float4 w0 = ((const float4*)(Wl + ko))[0];
                float4 w1 = ((const float4*)(Wl + ko))[1];
                #pragma unroll
                for (int mt = 0; mt < 2; ++mt) {
                    const float* gp = Ag + rel_[mt] + ko;
                    float4 ga  = ((const float4*)gp)[0];
                    float4 gb2 = ((const float4*)gp)[1];
                    float xs = xs_[mt];
                    float a0 = fmaxf(ga.x  + xs * w0.x, 0.f);
                    float a1 = fmaxf(ga.y  + xs * w0.y, 0.f);
                    float a2 = fmaxf(ga.z  + xs * w0.z, 0.f);
                    float a3 = fmaxf(ga.w  + xs * w0.w, 0.f);
                    float a4 = fmaxf(gb2.x + xs * w1.x, 0.f);
                    float a5 = fmaxf(gb2.y + xs * w1.y, 0.f);
                    float a6 = fmaxf(gb2.z + xs * w1.z, 0.f);
                    float a7 = fmaxf(gb2.w + xs * w1.w, 0.f);
                    af[mt].u.x = pk2bf(a0, a1); af[mt].u.y = pk2bf(a2, a3);
                    af[mt].u.z = pk2bf(a4, a5); af[mt].u.w = pk2bf(a6, a7);
                }
            }

            // ---- both col-halves share the A frags; B in groups of 4 ----
            #pragma unroll
            for (int hf = 0; hf < 2; ++hf) {
                const unsigned short* Bl = (const unsigned short*)(smem + (kc & 1) * 32768 + hf * 16384);
                #pragma unroll
                for (int g = 0; g < 2; ++g) {
                    bf16x8 bfr[4];
                    #pragma unroll
                    for (int nt = 0; nt < 4; ++nt)
                        bfr[nt] = *(const bf16x8*)(Bl + (cl * 128 + (g * 4 + nt) * 16 + l16) * 8);
                    #pragma unroll
                    for (int mt = 0; mt < 2; ++mt)
                        #pragma unroll
                        for (int nt = 0; nt < 4; ++nt)
                            acc[mt][hf * 8 + g * 4 + nt] = __builtin_amdgcn_mfma_f32_16x16x32_bf16(
                                af[mt].v, bfr[nt], acc[mt][hf * 8 + g * 4 + nt], 0, 0, 0);
                }
            }
        }
    }

    // ---- epilogue: relu(+ib2), dot with iw3 over all 256 cols ----
    float pf[2][4];
    #pragma unroll
    for (int mt = 0; mt < 2; ++mt)
        #pragma unroll
        for (int i = 0; i < 4; ++i) pf[mt][i] = 0.f;
    #pragma unroll
    for (int idx = 0; idx < 16; ++idx) {
        int n = idx * 16 + l16;               // global col: idx = hf*8 + nt_local
        float bias = ib2[n], w3 = iw3[n];
        #pragma unroll
        for (int mt = 0; mt < 2; ++mt)
            #pragma unroll
            for (int i = 0; i < 4; ++i) {
                float v = acc[mt][idx][i] + bias;
                v = v > 0.f ? v : 0.f;
                pf[mt][i] += v * w3;
            }
    }
    __syncthreads();     // all Bl/Ag reads done; smem becomes Pp/Cc
    #pragma unroll
    for (int mt = 0; mt < 2; ++mt)
        #pragma unroll
        for (int i = 0; i < 4; ++i) {
            int row = w * 32 + mt * 16 + quad * 4 + i;   // 0..255
            Pp[row * 20 + l16] = pf[mt][i];
        }
    __syncthreads();
    if (tid < 256) {
        const float4* pp = (const float4*)(Pp + tid * 20);
        float4 v0 = pp[0], v1 = pp[1], v2 = pp[2], v3 = pp[3];
        float s = v0.x + v0.y + v0.z + v0.w + v1.x + v1.y + v1.z + v1.w
                + v2.x + v2.y + v2.z + v2.w + v3.x + v3.y + v3.z + v3.w;
        unsigned bl = (unsigned)(((unsigned long long)(unsigned)tid * 657931ull) >> 25);  // tid/51
        int p = tid - (int)bl * 51;
        float s2 = s + ib3[0];
        float f = s2 > 0.f ? s2 + 1.f : __expf(s2);      // elu+1
        Cc[tid] = cc[p] * f;                             // row 255 garbage, never read
    }
    __syncthreads();
    if (w < 5) {                                         // wave w reduces batch blo+w
        float v = 0.f;
        if (lane < 51) v = Cc[w * 51 + lane];
        #pragma unroll
        for (int mask = 1; mask < 64; mask <<= 1) v += __shfl_xor(v, mask, 64);
        int bg = blo + w;
        if (lane == 0 && bg < BATCH)
            out[bg] = scal[bg] * (0.5f * x[bg] * v) + offs[bg];
    }
}

extern "C" void kernel_launch(void* const* d_in, const int* in_sizes, int n_in,
                              void* d_out, int out_size, void* d_ws, size_t ws_size,
                              hipStream_t stream) {
    const float* x   = (const float*)d_in[0];
    const float* h   = (const float*)d_in[1];
    const float* iw1 = (const float*)d_in[2];
    const float* ib1 = (const float*)d_in[3];
    const float* iw2 = (const float*)d_in[4];
    const float* ib2 = (const float*)d_in[5];
    const float* iw3 = (const float*)d_in[6];
    const float* ib3 = (const float*)d_in[7];
    const float* nw1 = (const float*)d_in[8];
    const float* nb1 = (const float*)d_in[9];
    const float* nw2 = (const float*)d_in[10];
    const float* nb2 = (const float*)d_in[11];
    const float* nw3 = (const float*)d_in[12];
    const float* nb3 = (const float*)d_in[13];
    float* out = (float*)d_out;

    char* ws = (char*)d_ws;
    unsigned short* iw2p = (unsigned short*)(ws + OFF_IW2P);
    float* w1xs  = (float*)(ws + OFF_W1X);
    float* cc    = (float*)(ws + OFF_CC);
    float* steps = (float*)(ws + OFF_STEPS);
    float* offs  = (float*)(ws + OFF_OFFS);
    float* scal  = (float*)(ws + OFF_SCAL);
    float* g1    = (float*)(ws + OFF_G1);

    k1_prep<<<dim3(897), dim3(256), 0, stream>>>(iw2, iw1, ib1, h, nw1, nb1,
                                                 nw2, nb2, nw3, nb3,
                                                 iw2p, w1xs, cc, steps, g1, offs, scal);
    k2_main<<<dim3(NK2), dim3(512), 0, stream>>>(x, g1, w1xs, iw2p, ib2, iw3,
                                                 steps, cc, ib3, offs, scal, out);
}